// Round 4
// baseline (121.406 us; speedup 1.0000x reference)
//
#include <hip/hip_runtime.h>
#include <math.h>

// ---------------------------------------------------------------------------
// Problem constants (from setup_inputs)
#define NPIX   589824      // 768*768
#define NEIK   100000
#define NSDF   100000
#define PP     50000
#define SPTS   8192        // points per cloud

// Kernel A: chamfer blocks first (longest pole), then fused sums regions
#define B_CH   512         // 2 dirs x 8 src-chunks(1024) x 32 dst-chunks(256)
#define B_PIX  576         // 576*256 thr, 4 pixels each = NPIX
#define B_EIK  98          // 98*256*4 = 100352, guard at 25000 groups
#define B_SDF  98
#define B_CON  196         // 196*256 = 50176 threads, 1 point each, guard 50000
#define GRID_A (B_CH + B_PIX + B_EIK + B_SDF + B_CON)   // 1480

// Kernel B: depth pass 2 + chamfer min-reduce + fence-free last-block finalize
#define B_DEP  576         // 576*256*4 == NPIX exactly
#define B_RED  64          // 64*256 = 16384 = 2*SPTS src points
#define GRID_B (B_DEP + B_RED)                           // 640

// ---------------------------------------------------------------------------
// Workspace layout (32-bit words). k_main partials are atomic-free direct
// stores (unique slot per block, no init needed; kernel boundary flushes).
// k_pass2 -> finalize communication uses DEVICE-SCOPE ATOMICS ONLY:
//   R2 post-mortem: per-block __threadfence costs +45us (cross-XCD L2
//   writeback in 640 blocks). Atomics execute at the coherent point, so
//   ordering data-atomic -> counter-atomic needs only s_waitcnt vmcnt(0)
//   (no wbl2), and only the single last block pays coherent readback.
#define OFF_MASK 0         // 576  (kernel A pixel blocks)
#define OFF_NERR 576       // 576
#define OFF_DEN  1152      // 576
#define OFF_NUM  1728      // 576
#define OFF_BCE  2304      // 576
#define OFF_EIK  2880      // 98
#define OFF_SDF  2978      // 98
#define OFF_CON  3076      // 196
#define OFF_VIS  3272      // 196
#define OFF_DEPS 4096      // 8 atomic slots, stride 16 (depth totals)
#define OFF_PCS  4224      // 8 atomic slots, stride 16 (pc totals)
#define OFF_CNT  4344      // completion counter (zeroed by k_main)
#define OFF_PART 4352      // chamfer partial mins: [dir*32+dc][s] = 2*32*8192
                           // words = 524288 (2 MB); total ws use ~2.07 MB

typedef float f32x2 __attribute__((ext_vector_type(2)));

// packed f32 FMA: d.lo = a.lo*b.lo+c.lo, d.hi = a.hi*b.hi+c.hi (IEEE fma both)
// verified bit-exact vs scalar path in R2/R3 (absmax 0.0)
__device__ __forceinline__ f32x2 pk_fma(f32x2 a, f32x2 b, f32x2 c) {
    f32x2 d;
    asm("v_pk_fma_f32 %0, %1, %2, %3" : "=v"(d) : "v"(a), "v"(b), "v"(c));
    return d;
}

__device__ __forceinline__ float nan0(float x) { return isfinite(x) ? x : 0.0f; }

__device__ __forceinline__ float waveReduce(float v) {
    v += __shfl_down(v, 32); v += __shfl_down(v, 16); v += __shfl_down(v, 8);
    v += __shfl_down(v, 4);  v += __shfl_down(v, 2);  v += __shfl_down(v, 1);
    return v;
}

// valid on thread 0 only; block must be 256 threads (4 waves)
__device__ __forceinline__ float blockReduce(float v, float* sbuf) {
    v = waveReduce(v);
    int lane = threadIdx.x & 63, w = threadIdx.x >> 6;
    __syncthreads();                  // protect sbuf across back-to-back calls
    if (lane == 0) sbuf[w] = v;
    __syncthreads();
    float r = 0.0f;
    if (threadIdx.x == 0) r = sbuf[0] + sbuf[1] + sbuf[2] + sbuf[3];
    return r;
}

union F12 { float4 v[3]; float f[12]; };

// ---------------------------------------------------------------------------
// Kernel A: chamfer rank-min partials + all single-pass sums. No atomics.
// Last block additionally zeroes the k_pass2 atomic slots + counter
// (plain stores; flushed at kernel end, visible to k_pass2).
__global__ __launch_bounds__(256) void k_main(
    const float* __restrict__ normal_pred, const float* __restrict__ normal_gt,
    const float* __restrict__ depth_pred,  const float* __restrict__ depth_gt,
    const float* __restrict__ mask,        const float* __restrict__ comp_mask,
    const float* __restrict__ gradients,   const float* __restrict__ sdf,
    const float* __restrict__ nwa,         const float* __restrict__ vm,
    const float* __restrict__ wts,
    const float* __restrict__ X,           const float* __restrict__ Y,
    float* __restrict__ ws)
{
    __shared__ f32x2 yb0[128], yb1[128], yb2[128], ybw[128];  // SoA dst cache
    __shared__ float sbuf[4];
    int b = blockIdx.x;
    int t = threadIdx.x;

    if (b == GRID_A - 1) {            // zero the kernel-B atomic slots
        if (t < 8)       ws[OFF_DEPS + t * 16] = 0.0f;
        else if (t < 16) ws[OFF_PCS + (t - 8) * 16] = 0.0f;
        else if (t == 16) ((unsigned*)ws)[OFF_CNT] = 0u;
    }

    if (b < B_CH) {
        // Chamfer: rank value r = 0.5*|y|^2 - x.y; d2/2 = min_r + 0.5*|x|^2.
        // Two dst points per packed FMA lane-pair; each block owns a unique
        // (dir, src-chunk, dst-chunk) -> direct store, no atomics.
        int dir = b >> 8;            // 0: X->Y, 1: Y->X
        int r   = b & 255;
        int sc  = r >> 5;            // 0..7 src chunk of 1024
        int dc  = r & 31;            // 0..31 dst chunk of 256
        const float* src = dir ? Y : X;
        const float* dst = dir ? X : Y;
        {
            int d = dc * 256 + t;
            float y0 = dst[3*d], y1 = dst[3*d+1], y2 = dst[3*d+2];
            ((float*)yb0)[t] = y0;
            ((float*)yb1)[t] = y1;
            ((float*)yb2)[t] = y2;
            ((float*)ybw)[t] = 0.5f * (y0*y0 + y1*y1 + y2*y2);
        }
        f32x2 nxp0[4], nxp1[4], nxp2[4];
        float hx2[4], mn[4];
#pragma unroll
        for (int j = 0; j < 4; ++j) {
            int s = sc * 1024 + t + j * 256;
            float x0 = src[3*s], x1 = src[3*s+1], x2 = src[3*s+2];
            nxp0[j] = (f32x2){-x0, -x0};
            nxp1[j] = (f32x2){-x1, -x1};
            nxp2[j] = (f32x2){-x2, -x2};
            hx2[j] = 0.5f * (x0*x0 + x1*x1 + x2*x2);
            mn[j]  = 1e30f;
        }
        __syncthreads();
#pragma unroll 4
        for (int i = 0; i < 128; ++i) {
            f32x2 Y0 = yb0[i];         // uniform address -> LDS broadcast
            f32x2 Y1 = yb1[i];
            f32x2 Y2 = yb2[i];
            f32x2 YW = ybw[i];
#pragma unroll
            for (int j = 0; j < 4; ++j) {
                f32x2 r2 = pk_fma(nxp0[j], Y0, YW);
                r2 = pk_fma(nxp1[j], Y1, r2);
                r2 = pk_fma(nxp2[j], Y2, r2);
                mn[j] = fminf(mn[j], fminf(r2.x, r2.y));   // -> v_min3_f32
            }
        }
        float* part = ws + OFF_PART + (dir * 32 + dc) * SPTS;
#pragma unroll
        for (int j = 0; j < 4; ++j) {
            int s = sc * 1024 + t + j * 256;
            part[s] = mn[j] + hx2[j];                  // coalesced 256B store/wave
        }
        return;
    }

    int bs = b - B_CH;
    if (bs < B_PIX) {
        int g = bs * 256 + t;                    // pixel group, 4 pixels
        float4 m4 = ((const float4*)mask)[g];
        float4 c4 = ((const float4*)comp_mask)[g];
        float4 dg4 = ((const float4*)depth_gt)[g];
        float4 dp4 = ((const float4*)depth_pred)[g];
        F12 np, ng;
        np.v[0] = ((const float4*)normal_pred)[3*g];
        np.v[1] = ((const float4*)normal_pred)[3*g+1];
        np.v[2] = ((const float4*)normal_pred)[3*g+2];
        ng.v[0] = ((const float4*)normal_gt)[3*g];
        ng.v[1] = ((const float4*)normal_gt)[3*g+1];
        ng.v[2] = ((const float4*)normal_gt)[3*g+2];
        float mm[4] = { m4.x, m4.y, m4.z, m4.w };
        float cc[4] = { c4.x, c4.y, c4.z, c4.w };
        float gg[4] = { dg4.x, dg4.y, dg4.z, dg4.w };
        float pp[4] = { dp4.x, dp4.y, dp4.z, dp4.w };
        float s_mask = 0, s_nerr = 0, s_den = 0, s_num = 0, s_bce = 0;
#pragma unroll
        for (int k = 0; k < 4; ++k) {
            float m = mm[k] > 0.5f ? 1.0f : 0.0f;
            s_mask += m;
            float e0 = nan0(np.f[3*k])   - nan0(ng.f[3*k]);
            float e1 = nan0(np.f[3*k+1]) - nan0(ng.f[3*k+1]);
            float e2 = nan0(np.f[3*k+2]) - nan0(ng.f[3*k+2]);
            s_nerr += m * (e0*e0 + e1*e1 + e2*e2);
            float vg = (m == 1.0f) ? nan0(gg[k]) : 0.0f;
            float vp = (m == 1.0f) ? nan0(pp[k]) : 0.0f;
            s_den += vg * vg;
            s_num += vg * vp;
            float c = cc[k];
            c = fminf(fmaxf(c, 0.0f), 1.0f);     // clip; +inf->1, -inf->0
            if (isnan(c)) c = 0.5f;              // nan->0.5
            c = fminf(fmaxf(c, 1e-5f), 1.0f - 1e-5f);
            s_bce -= m * __logf(c) + (1.0f - m) * __logf(1.0f - c);
        }
        float r;
        r = blockReduce(s_mask, sbuf); if (t == 0) ws[OFF_MASK + bs] = r;
        r = blockReduce(s_nerr, sbuf); if (t == 0) ws[OFF_NERR + bs] = r;
        r = blockReduce(s_den,  sbuf); if (t == 0) ws[OFF_DEN  + bs] = r;
        r = blockReduce(s_num,  sbuf); if (t == 0) ws[OFF_NUM  + bs] = r;
        r = blockReduce(s_bce,  sbuf); if (t == 0) ws[OFF_BCE  + bs] = r;
    } else if (bs < B_PIX + B_EIK) {
        int eb = bs - B_PIX;
        int i = eb * 256 + t;                    // group of 4 points
        float acc = 0;
        if (i < NEIK / 4) {
            F12 gr;
            gr.v[0] = ((const float4*)gradients)[3*i];
            gr.v[1] = ((const float4*)gradients)[3*i+1];
            gr.v[2] = ((const float4*)gradients)[3*i+2];
#pragma unroll
            for (int k = 0; k < 4; ++k) {
                float g0 = gr.f[3*k], g1 = gr.f[3*k+1], g2 = gr.f[3*k+2];
                float n = sqrtf(g0*g0 + g1*g1 + g2*g2) - 1.0f;
                acc += n * n;
            }
        }
        float r = blockReduce(acc, sbuf); if (t == 0) ws[OFF_EIK + eb] = r;
    } else if (bs < B_PIX + B_EIK + B_SDF) {
        int db = bs - B_PIX - B_EIK;
        int i = db * 256 + t;                    // group of 4
        float acc = 0;
        if (i < NSDF / 4) {
            float4 s4 = ((const float4*)sdf)[i];
            acc = fabsf(s4.x) + fabsf(s4.y) + fabsf(s4.z) + fabsf(s4.w);
        }
        float r = blockReduce(acc, sbuf); if (t == 0) ws[OFF_SDF + db] = r;
    } else {
        int cb = bs - B_PIX - B_EIK - B_SDF;
        int p = cb * 256 + t;                    // one point, 3 cam pairs
        float s_con = 0, s_vis = 0;
        if (p < PP) {
            F12 a;
            a.v[0] = ((const float4*)nwa)[3*p];
            a.v[1] = ((const float4*)nwa)[3*p+1];
            a.v[2] = ((const float4*)nwa)[3*p+2];
            float4 v4 = ((const float4*)vm)[p];
            float vv[4] = { v4.x, v4.y, v4.z, v4.w };
            float w = wts[p];
#pragma unroll
            for (int pr = 0; pr < 3; ++pr) {
                float d0 = a.f[3*pr]   - a.f[3*pr+3];
                float d1 = a.f[3*pr+1] - a.f[3*pr+4];
                float d2 = a.f[3*pr+2] - a.f[3*pr+5];
                float mse = d0*d0 + d1*d1 + d2*d2;
                float vis = vv[pr] * vv[pr+1];
                s_vis += vis;
                s_con += mse * vis * w;
            }
        }
        float r;
        r = blockReduce(s_con, sbuf); if (t == 0) ws[OFF_CON + cb] = r;
        r = blockReduce(s_vis, sbuf); if (t == 0) ws[OFF_VIS + cb] = r;
    }
}

// ---------------------------------------------------------------------------
// Kernel B: depth pass 2 + chamfer 32-way min-reduce. Block totals go to
// 8-way-spread slots via device-scope atomicAdd (coherent point). Last
// arriving block (fence-free counter protocol) assembles the loss.
__global__ __launch_bounds__(256) void k_pass2(
    const float* __restrict__ depth_pred, const float* __restrict__ depth_gt,
    const float* __restrict__ mask, float* __restrict__ ws,
    float* __restrict__ out)
{
    __shared__ float sbuf[4];
    __shared__ float sc2[2];
    __shared__ float slots[16];
    __shared__ float qq[8];
    __shared__ int lastFlag;
    int b = blockIdx.x;
    int t = threadIdx.x;
    if (b < B_DEP) {
        // cooperative sum of the 576 den/num partials (L2-resident)
        float dpart = 0, npart = 0;
        for (int i = t; i < B_PIX; i += 256) {
            dpart += ws[OFF_DEN + i];
            npart += ws[OFF_NUM + i];
        }
        float r = blockReduce(dpart, sbuf); if (t == 0) sc2[0] = r;
        r = blockReduce(npart, sbuf);       if (t == 0) sc2[1] = r;
        __syncthreads();
        float scale = sc2[1] / sc2[0];
        if (!isfinite(scale)) scale = 1.0f;          // nan_to_num(nan=1, +-inf=1)
        int g = b * 256 + t;                         // 4 pixels per thread
        float4 m4  = ((const float4*)mask)[g];
        float4 dg4 = ((const float4*)depth_gt)[g];
        float4 dp4 = ((const float4*)depth_pred)[g];
        float mm[4] = { m4.x, m4.y, m4.z, m4.w };
        float gg[4] = { dg4.x, dg4.y, dg4.z, dg4.w };
        float pp[4] = { dp4.x, dp4.y, dp4.z, dp4.w };
        float acc = 0;
#pragma unroll
        for (int k = 0; k < 4; ++k) {
            float m  = mm[k] > 0.5f ? 1.0f : 0.0f;
            float vg = (m == 1.0f) ? nan0(gg[k]) : 0.0f;
            float vp = (m == 1.0f) ? nan0(pp[k]) : 0.0f;
            acc += fabsf(vg * scale - vp);
        }
        float tot = blockReduce(acc, sbuf);
        if (t == 0) atomicAdd(&ws[OFF_DEPS + (b & 7) * 16], tot);
    } else {
        // chamfer reduce: one thread per src point, min over 32 dst-chunk partials
        int p = (b - B_DEP) * 256 + t;               // 0..16383, exact
        int dir = p >> 13;
        int s = p & (SPTS - 1);
        const float* part = ws + OFF_PART + dir * 32 * SPTS;
        float vmin = part[s];                        // coalesced across lanes
#pragma unroll
        for (int dc = 1; dc < 32; ++dc)
            vmin = fminf(vmin, part[dc * SPTS + s]);
        float pc = sqrtf(fmaxf(2.0f * vmin, 0.0f));  // back to L2 distance
        float r = blockReduce(pc, sbuf);
        if (t == 0) atomicAdd(&ws[OFF_PCS + (b & 7) * 16], r);
    }

    // ---- fence-free completion: data went through coherent-point atomics;
    // order data-atomic before counter-atomic with a bare vmcnt wait (no
    // L2 writeback needed, unlike __threadfence -- see R2 post-mortem).
    if (t == 0) {
        asm volatile("s_waitcnt vmcnt(0)" ::: "memory");
        unsigned old = __hip_atomic_fetch_add((unsigned*)ws + OFF_CNT, 1u,
                                              __ATOMIC_RELAXED,
                                              __HIP_MEMORY_SCOPE_AGENT);
        lastFlag = (old == GRID_B - 1);
    }
    __syncthreads();
    if (!lastFlag) return;

    // ---- last block: assemble. k_main partials are plain loads (flushed at
    // its kernel end); k_pass2 totals are read back with agent-scope atomic
    // loads (coherent point, immune to stale clean lines).
    if (t < 8) {
        slots[t] = __hip_atomic_load(&ws[OFF_DEPS + t * 16],
                                     __ATOMIC_RELAXED, __HIP_MEMORY_SCOPE_AGENT);
    } else if (t < 16) {
        slots[t] = __hip_atomic_load(&ws[OFF_PCS + (t - 8) * 16],
                                     __ATOMIC_RELAXED, __HIP_MEMORY_SCOPE_AGENT);
    }
    // wave-parallel region sums: wave w -> one 576 region + one small region
    int w = t >> 6, lane = t & 63;
    const int offA[4] = { OFF_MASK, OFF_NERR, OFF_DEN, OFF_BCE };
    const int offB[4] = { OFF_EIK, OFF_SDF, OFF_CON, OFF_VIS };
    const int nB[4]   = { B_EIK, B_SDF, B_CON, B_CON };
    float sA = 0, sB = 0;
    for (int i = lane; i < B_PIX; i += 64) sA += ws[offA[w] + i];
    for (int i = lane; i < nB[w]; i += 64) sB += ws[offB[w] + i];
    sA = waveReduce(sA); sB = waveReduce(sB);
    if (lane == 0) { qq[w] = sA; qq[4 + w] = sB; }
    __syncthreads();
    if (t == 0) {
        float dep = 0, pcs = 0;
#pragma unroll
        for (int i = 0; i < 8; ++i) { dep += slots[i]; pcs += slots[8 + i]; }
        float mask_sum = qq[0] + 1e-5f;
        float normal_loss = qq[1] / mask_sum;
        float depth_loss = dep / (mask_sum + 1e-8f);
        if (qq[2] < 1e-10f) depth_loss = 0.0f;
        depth_loss = nan0(depth_loss);
        float pc_loss  = pcs / (float)SPTS;      // both dirs share the /8192
        float bce      = qq[7 - 4 + 0] * 0.0f + qq[3] / (float)NPIX; // BCE = wave3 A
        float eik      = qq[4] / (float)NEIK;
        float sdf_loss = qq[5] / (float)NSDF;
        float con      = qq[7] > 0.0f ? qq[6] / qq[7] : 0.0f;
        out[0] = normal_loss + depth_loss + pc_loss + bce + eik + sdf_loss + con;
    }
}

// ---------------------------------------------------------------------------
extern "C" void kernel_launch(void* const* d_in, const int* in_sizes, int n_in,
                              void* d_out, int out_size, void* d_ws, size_t ws_size,
                              hipStream_t stream) {
    const float* normal_pred = (const float*)d_in[0];
    const float* normal_gt   = (const float*)d_in[1];
    const float* depth_pred  = (const float*)d_in[2];
    const float* depth_gt    = (const float*)d_in[3];
    const float* X           = (const float*)d_in[4];
    const float* Y           = (const float*)d_in[5];
    const float* mask        = (const float*)d_in[6];
    const float* comp_mask   = (const float*)d_in[7];
    const float* gradients   = (const float*)d_in[8];
    const float* sdf         = (const float*)d_in[9];
    const float* nwa         = (const float*)d_in[10];
    const float* vm          = (const float*)d_in[11];
    const float* wts         = (const float*)d_in[12];
    float* ws  = (float*)d_ws;
    float* out = (float*)d_out;

    k_main<<<dim3(GRID_A), dim3(256), 0, stream>>>(
        normal_pred, normal_gt, depth_pred, depth_gt, mask, comp_mask,
        gradients, sdf, nwa, vm, wts, X, Y, ws);
    k_pass2<<<dim3(GRID_B), dim3(256), 0, stream>>>(
        depth_pred, depth_gt, mask, ws, out);
}

// Round 5
// 114.431 us; speedup vs baseline: 1.0610x; 1.0610x over previous
//
#include <hip/hip_runtime.h>
#include <math.h>

// ---------------------------------------------------------------------------
// Problem constants (from setup_inputs)
#define NPIX   589824      // 768*768
#define NEIK   100000
#define NSDF   100000
#define PP     50000
#define SPTS   8192        // points per cloud

// Kernel A: chamfer blocks first (longest pole), then fused sums regions
#define B_CH   512         // 2 dirs x 8 src-chunks(1024) x 32 dst-chunks(256)
#define B_PIX  576         // 576*256 thr, 4 pixels each = NPIX
#define B_EIK  98          // 98*256*4 = 100352, guard at 25000 groups
#define B_SDF  98
#define B_CON  196         // 196*256 = 50176 threads, 1 point each, guard 50000
#define GRID_A (B_CH + B_PIX + B_EIK + B_SDF + B_CON)   // 1480

// Kernel B: depth pass 2 + chamfer min-reduce
#define B_DEP  576         // 576*256*4 == NPIX exactly
#define B_RED  64          // 64*256 = 16384 = 2*SPTS src points
#define GRID_B (B_DEP + B_RED)                           // 640

// ---------------------------------------------------------------------------
// Workspace layout (32-bit words). ALL accumulators are atomic-free:
// each block direct-stores its partial into a unique slot, so no init
// kernel is needed (poisoned workspace is fully overwritten before read).
// SESSION LEDGER (do not re-try):
//  - R2: last-block finalize w/ per-block __threadfence: +43us (cross-XCD
//    L2 writeback storm in 640 blocks).
//  - R4: same merge w/ coherent-point atomics + vmcnt ordering: still +3-6us.
//    Kernel boundaries are the cheapest device-wide sync on gfx950.
//  - R3: v_pk_fma_f32 chamfer: neutral (packed f32 FMA is FLOP-rate-neutral
//    on CDNA4; chamfer is FLOP-bound, not issue-bound).
#define OFF_MASK 0         // 576  (kernel A pixel blocks)
#define OFF_NERR 576       // 576
#define OFF_DEN  1152      // 576
#define OFF_NUM  1728      // 576
#define OFF_BCE  2304      // 576
#define OFF_EIK  2880      // 98
#define OFF_SDF  2978      // 98
#define OFF_CON  3076      // 196
#define OFF_VIS  3272      // 196
#define OFF_DEP  3468      // 576  (kernel B depth blocks)
#define OFF_PC   4044      // 64   (kernel B reduce blocks)
#define OFF_PART 4352      // chamfer partial mins: [dir*32+dc][s] = 2*32*8192
                           // words = 524288 (2 MB); total ws use ~2.07 MB

__device__ __forceinline__ float nan0(float x) { return isfinite(x) ? x : 0.0f; }

__device__ __forceinline__ float waveReduce(float v) {
    v += __shfl_down(v, 32); v += __shfl_down(v, 16); v += __shfl_down(v, 8);
    v += __shfl_down(v, 4);  v += __shfl_down(v, 2);  v += __shfl_down(v, 1);
    return v;
}

// valid on thread 0 only; block must be 256 threads (4 waves)
__device__ __forceinline__ float blockReduce(float v, float* sbuf) {
    v = waveReduce(v);
    int lane = threadIdx.x & 63, w = threadIdx.x >> 6;
    __syncthreads();                  // protect sbuf across back-to-back calls
    if (lane == 0) sbuf[w] = v;
    __syncthreads();
    float r = 0.0f;
    if (threadIdx.x == 0) r = sbuf[0] + sbuf[1] + sbuf[2] + sbuf[3];
    return r;
}

union F12 { float4 v[3]; float f[12]; };

// ---------------------------------------------------------------------------
// Kernel A: chamfer rank-min partials + all single-pass sums. No atomics.
__global__ __launch_bounds__(256) void k_main(
    const float* __restrict__ normal_pred, const float* __restrict__ normal_gt,
    const float* __restrict__ depth_pred,  const float* __restrict__ depth_gt,
    const float* __restrict__ mask,        const float* __restrict__ comp_mask,
    const float* __restrict__ gradients,   const float* __restrict__ sdf,
    const float* __restrict__ nwa,         const float* __restrict__ vm,
    const float* __restrict__ wts,
    const float* __restrict__ X,           const float* __restrict__ Y,
    float* __restrict__ ws)
{
    __shared__ float4 ybuf[256];
    __shared__ float  sbuf[4];
    int b = blockIdx.x;
    int t = threadIdx.x;

    if (b < B_CH) {
        // Chamfer: rank value r = 0.5*|y|^2 - x.y (3 FMA); d2/2 = min_r + 0.5*|x|^2.
        // Each block owns a unique (dir, src-chunk, dst-chunk) -> direct store.
        int dir = b >> 8;            // 0: X->Y, 1: Y->X
        int r   = b & 255;
        int sc  = r >> 5;            // 0..7 src chunk of 1024
        int dc  = r & 31;            // 0..31 dst chunk of 256
        const float* src = dir ? Y : X;
        const float* dst = dir ? X : Y;
        {
            int d = dc * 256 + t;
            float y0 = dst[3*d], y1 = dst[3*d+1], y2 = dst[3*d+2];
            ybuf[t] = make_float4(y0, y1, y2, 0.5f * (y0*y0 + y1*y1 + y2*y2));
        }
        float nx0[4], nx1[4], nx2[4], hx2[4], mn[4];
#pragma unroll
        for (int j = 0; j < 4; ++j) {
            int s = sc * 1024 + t + j * 256;
            float x0 = src[3*s], x1 = src[3*s+1], x2 = src[3*s+2];
            nx0[j] = -x0; nx1[j] = -x1; nx2[j] = -x2;
            hx2[j] = 0.5f * (x0*x0 + x1*x1 + x2*x2);
            mn[j]  = 1e30f;
        }
        __syncthreads();
#pragma unroll 2
        for (int dd = 0; dd < 256; dd += 2) {
            float4 ya = ybuf[dd];      // uniform address -> LDS broadcast
            float4 yb = ybuf[dd + 1];
#pragma unroll
            for (int j = 0; j < 4; ++j) {
                float ra = fmaf(nx0[j], ya.x, ya.w);
                ra = fmaf(nx1[j], ya.y, ra);
                ra = fmaf(nx2[j], ya.z, ra);
                float rb = fmaf(nx0[j], yb.x, yb.w);
                rb = fmaf(nx1[j], yb.y, rb);
                rb = fmaf(nx2[j], yb.z, rb);
                mn[j] = fminf(mn[j], fminf(ra, rb));   // -> v_min3_f32
            }
        }
        float* part = ws + OFF_PART + (dir * 32 + dc) * SPTS;
#pragma unroll
        for (int j = 0; j < 4; ++j) {
            int s = sc * 1024 + t + j * 256;
            part[s] = mn[j] + hx2[j];                  // coalesced 256B store/wave
        }
        return;
    }

    int bs = b - B_CH;
    if (bs < B_PIX) {
        int g = bs * 256 + t;                    // pixel group, 4 pixels
        float4 m4 = ((const float4*)mask)[g];
        float4 c4 = ((const float4*)comp_mask)[g];
        float4 dg4 = ((const float4*)depth_gt)[g];
        float4 dp4 = ((const float4*)depth_pred)[g];
        F12 np, ng;
        np.v[0] = ((const float4*)normal_pred)[3*g];
        np.v[1] = ((const float4*)normal_pred)[3*g+1];
        np.v[2] = ((const float4*)normal_pred)[3*g+2];
        ng.v[0] = ((const float4*)normal_gt)[3*g];
        ng.v[1] = ((const float4*)normal_gt)[3*g+1];
        ng.v[2] = ((const float4*)normal_gt)[3*g+2];
        float mm[4] = { m4.x, m4.y, m4.z, m4.w };
        float cc[4] = { c4.x, c4.y, c4.z, c4.w };
        float gg[4] = { dg4.x, dg4.y, dg4.z, dg4.w };
        float pp[4] = { dp4.x, dp4.y, dp4.z, dp4.w };
        float s_mask = 0, s_nerr = 0, s_den = 0, s_num = 0, s_bce = 0;
#pragma unroll
        for (int k = 0; k < 4; ++k) {
            float m = mm[k] > 0.5f ? 1.0f : 0.0f;
            s_mask += m;
            float e0 = nan0(np.f[3*k])   - nan0(ng.f[3*k]);
            float e1 = nan0(np.f[3*k+1]) - nan0(ng.f[3*k+1]);
            float e2 = nan0(np.f[3*k+2]) - nan0(ng.f[3*k+2]);
            s_nerr += m * (e0*e0 + e1*e1 + e2*e2);
            float vg = (m == 1.0f) ? nan0(gg[k]) : 0.0f;
            float vp = (m == 1.0f) ? nan0(pp[k]) : 0.0f;
            s_den += vg * vg;
            s_num += vg * vp;
            float c = cc[k];
            c = fminf(fmaxf(c, 0.0f), 1.0f);     // clip; +inf->1, -inf->0
            if (isnan(c)) c = 0.5f;              // nan->0.5
            c = fminf(fmaxf(c, 1e-5f), 1.0f - 1e-5f);
            s_bce -= m * __logf(c) + (1.0f - m) * __logf(1.0f - c);
        }
        float r;
        r = blockReduce(s_mask, sbuf); if (t == 0) ws[OFF_MASK + bs] = r;
        r = blockReduce(s_nerr, sbuf); if (t == 0) ws[OFF_NERR + bs] = r;
        r = blockReduce(s_den,  sbuf); if (t == 0) ws[OFF_DEN  + bs] = r;
        r = blockReduce(s_num,  sbuf); if (t == 0) ws[OFF_NUM  + bs] = r;
        r = blockReduce(s_bce,  sbuf); if (t == 0) ws[OFF_BCE  + bs] = r;
    } else if (bs < B_PIX + B_EIK) {
        int eb = bs - B_PIX;
        int i = eb * 256 + t;                    // group of 4 points
        float acc = 0;
        if (i < NEIK / 4) {
            F12 gr;
            gr.v[0] = ((const float4*)gradients)[3*i];
            gr.v[1] = ((const float4*)gradients)[3*i+1];
            gr.v[2] = ((const float4*)gradients)[3*i+2];
#pragma unroll
            for (int k = 0; k < 4; ++k) {
                float g0 = gr.f[3*k], g1 = gr.f[3*k+1], g2 = gr.f[3*k+2];
                float n = sqrtf(g0*g0 + g1*g1 + g2*g2) - 1.0f;
                acc += n * n;
            }
        }
        float r = blockReduce(acc, sbuf); if (t == 0) ws[OFF_EIK + eb] = r;
    } else if (bs < B_PIX + B_EIK + B_SDF) {
        int db = bs - B_PIX - B_EIK;
        int i = db * 256 + t;                    // group of 4
        float acc = 0;
        if (i < NSDF / 4) {
            float4 s4 = ((const float4*)sdf)[i];
            acc = fabsf(s4.x) + fabsf(s4.y) + fabsf(s4.z) + fabsf(s4.w);
        }
        float r = blockReduce(acc, sbuf); if (t == 0) ws[OFF_SDF + db] = r;
    } else {
        int cb = bs - B_PIX - B_EIK - B_SDF;
        int p = cb * 256 + t;                    // one point, 3 cam pairs
        float s_con = 0, s_vis = 0;
        if (p < PP) {
            F12 a;
            a.v[0] = ((const float4*)nwa)[3*p];
            a.v[1] = ((const float4*)nwa)[3*p+1];
            a.v[2] = ((const float4*)nwa)[3*p+2];
            float4 v4 = ((const float4*)vm)[p];
            float vv[4] = { v4.x, v4.y, v4.z, v4.w };
            float w = wts[p];
#pragma unroll
            for (int pr = 0; pr < 3; ++pr) {
                float d0 = a.f[3*pr]   - a.f[3*pr+3];
                float d1 = a.f[3*pr+1] - a.f[3*pr+4];
                float d2 = a.f[3*pr+2] - a.f[3*pr+5];
                float mse = d0*d0 + d1*d1 + d2*d2;
                float vis = vv[pr] * vv[pr+1];
                s_vis += vis;
                s_con += mse * vis * w;
            }
        }
        float r;
        r = blockReduce(s_con, sbuf); if (t == 0) ws[OFF_CON + cb] = r;
        r = blockReduce(s_vis, sbuf); if (t == 0) ws[OFF_VIS + cb] = r;
    }
}

// ---------------------------------------------------------------------------
// Kernel B: depth pass 2 (needs den/num totals from kernel A) + chamfer
// 32-way min-reduce with sqrt folded in. No atomics, no device fences.
__global__ __launch_bounds__(256) void k_pass2(
    const float* __restrict__ depth_pred, const float* __restrict__ depth_gt,
    const float* __restrict__ mask, float* __restrict__ ws)
{
    __shared__ float sbuf[4];
    __shared__ float sc2[2];
    int b = blockIdx.x;
    int t = threadIdx.x;
    if (b < B_DEP) {
        // cooperative sum of the 576 den/num partials (L2-resident)
        float dpart = 0, npart = 0;
        for (int i = t; i < B_PIX; i += 256) {
            dpart += ws[OFF_DEN + i];
            npart += ws[OFF_NUM + i];
        }
        float r = blockReduce(dpart, sbuf); if (t == 0) sc2[0] = r;
        r = blockReduce(npart, sbuf);       if (t == 0) sc2[1] = r;
        __syncthreads();
        float scale = sc2[1] / sc2[0];
        if (!isfinite(scale)) scale = 1.0f;          // nan_to_num(nan=1, +-inf=1)
        int g = b * 256 + t;                         // 4 pixels per thread
        float4 m4  = ((const float4*)mask)[g];
        float4 dg4 = ((const float4*)depth_gt)[g];
        float4 dp4 = ((const float4*)depth_pred)[g];
        float mm[4] = { m4.x, m4.y, m4.z, m4.w };
        float gg[4] = { dg4.x, dg4.y, dg4.z, dg4.w };
        float pp[4] = { dp4.x, dp4.y, dp4.z, dp4.w };
        float acc = 0;
#pragma unroll
        for (int k = 0; k < 4; ++k) {
            float m  = mm[k] > 0.5f ? 1.0f : 0.0f;
            float vg = (m == 1.0f) ? nan0(gg[k]) : 0.0f;
            float vp = (m == 1.0f) ? nan0(pp[k]) : 0.0f;
            acc += fabsf(vg * scale - vp);
        }
        float tot = blockReduce(acc, sbuf);
        if (t == 0) ws[OFF_DEP + b] = tot;
    } else {
        // chamfer reduce: one thread per src point, min over 32 dst-chunk partials
        int p = (b - B_DEP) * 256 + t;               // 0..16383, exact
        int dir = p >> 13;
        int s = p & (SPTS - 1);
        const float* part = ws + OFF_PART + dir * 32 * SPTS;
        float vmin = part[s];                        // coalesced across lanes
#pragma unroll
        for (int dc = 1; dc < 32; ++dc)
            vmin = fminf(vmin, part[dc * SPTS + s]);
        float pc = sqrtf(fmaxf(2.0f * vmin, 0.0f));  // back to L2 distance
        float r = blockReduce(pc, sbuf);
        if (t == 0) ws[OFF_PC + (b - B_DEP)] = r;
    }
}

// ---------------------------------------------------------------------------
// single-block finalize: sum each partial region, assemble the loss.
__global__ __launch_bounds__(256) void k_finalize(
    const float* __restrict__ ws, float* __restrict__ out)
{
    __shared__ float sbuf[4];
    __shared__ float q[10];
    int t = threadIdx.x;
    float a, r;
#define RED(off, n, slot) \
    a = 0; for (int i = t; i < (n); i += 256) a += ws[(off) + i]; \
    r = blockReduce(a, sbuf); if (t == 0) q[slot] = r;
    RED(OFF_MASK, B_PIX, 0)
    RED(OFF_NERR, B_PIX, 1)
    RED(OFF_DEN,  B_PIX, 2)
    RED(OFF_BCE,  B_PIX, 3)
    RED(OFF_EIK,  B_EIK, 4)
    RED(OFF_SDF,  B_SDF, 5)
    RED(OFF_CON,  B_CON, 6)
    RED(OFF_VIS,  B_CON, 7)
    RED(OFF_DEP,  B_DEP, 8)
    RED(OFF_PC,   B_RED, 9)
#undef RED
    __syncthreads();
    if (t == 0) {
        float mask_sum = q[0] + 1e-5f;
        float normal_loss = q[1] / mask_sum;
        float depth_loss = q[8] / (mask_sum + 1e-8f);
        if (q[2] < 1e-10f) depth_loss = 0.0f;
        depth_loss = nan0(depth_loss);
        float pc_loss  = q[9] / (float)SPTS;     // both dirs share the /8192
        float bce      = q[3] / (float)NPIX;
        float eik      = q[4] / (float)NEIK;
        float sdf_loss = q[5] / (float)NSDF;
        float con      = q[7] > 0.0f ? q[6] / q[7] : 0.0f;
        out[0] = normal_loss + depth_loss + pc_loss + bce + eik + sdf_loss + con;
    }
}

// ---------------------------------------------------------------------------
extern "C" void kernel_launch(void* const* d_in, const int* in_sizes, int n_in,
                              void* d_out, int out_size, void* d_ws, size_t ws_size,
                              hipStream_t stream) {
    const float* normal_pred = (const float*)d_in[0];
    const float* normal_gt   = (const float*)d_in[1];
    const float* depth_pred  = (const float*)d_in[2];
    const float* depth_gt    = (const float*)d_in[3];
    const float* X           = (const float*)d_in[4];
    const float* Y           = (const float*)d_in[5];
    const float* mask        = (const float*)d_in[6];
    const float* comp_mask   = (const float*)d_in[7];
    const float* gradients   = (const float*)d_in[8];
    const float* sdf         = (const float*)d_in[9];
    const float* nwa         = (const float*)d_in[10];
    const float* vm          = (const float*)d_in[11];
    const float* wts         = (const float*)d_in[12];
    float* ws  = (float*)d_ws;
    float* out = (float*)d_out;

    k_main<<<dim3(GRID_A), dim3(256), 0, stream>>>(
        normal_pred, normal_gt, depth_pred, depth_gt, mask, comp_mask,
        gradients, sdf, nwa, vm, wts, X, Y, ws);
    k_pass2<<<dim3(GRID_B), dim3(256), 0, stream>>>(depth_pred, depth_gt, mask, ws);
    k_finalize<<<dim3(1), dim3(256), 0, stream>>>(ws, out);
}